// Round 5
// baseline (245.725 us; speedup 1.0000x reference)
//
#include <hip/hip_runtime.h>

#define HW 4608      // 48*96
#define NB 16
#define CC 256
#define SS 64
#define EPS 1e-5f
#define NSPLIT 16    // k_graph split-K

typedef __attribute__((ext_vector_type(8))) short short8;
typedef __attribute__((ext_vector_type(4))) float f32x4;

__device__ __forceinline__ ushort f2bf(float f) {
    uint u = __float_as_uint(f);
    return (ushort)((u + 0x7FFFu + ((u >> 16) & 1u)) >> 16);
}

// ---------------- K0: pack W fragment-ready: Wf[cs][kq][r][j] bf16, c = cs*32+kq*8+j ----------
__global__ __launch_bounds__(256) void k_wf(const float* __restrict__ Ws,
                                            const float* __restrict__ Wp,
                                            ushort* __restrict__ Wf) {
    int idx = blockIdx.x * 256 + threadIdx.x;      // 0..32767
    int j = idx & 7, r = (idx >> 3) & 127, kq = (idx >> 10) & 3, cs = idx >> 12;
    int c = cs * 32 + kq * 8 + j;
    float v = (r < 64) ? Ws[r * CC + c] : Wp[(r - 64) * CC + c];
    Wf[idx] = f2bf(v);
}

// ---------------- K1: MFMA proj, LDS-staged, double-buffered, 1 barrier/step ----------------
// grid (36, NB), 256 thr (4 waves). Block tile 128r x 128hw; wave: all 128r x 32hw.
// K=C=256 in 8 steps of 32. LDS: fp32 x-tile [32c][128hw] pad 130, x2 buffers.
#define CPAD 130
__global__ __launch_bounds__(256) void k_proj(const float* __restrict__ x,
                                              const ushort* __restrict__ Wf,
                                              const float* __restrict__ bs,
                                              const float* __restrict__ bp,
                                              const float* __restrict__ edge,
                                              ushort* __restrict__ xsb,
                                              ushort* __restrict__ Eb,
                                              float* __restrict__ rsum) {
    __shared__ __align__(16) float Xs[2][32 * CPAD];
    int n = blockIdx.y, k0 = blockIdx.x * 128;
    int tid = threadIdx.x, lane = tid & 63, w = tid >> 6;
    int q = lane >> 4, li = lane & 15;
    int cst = tid >> 5;              // staging c base (0..7)
    int hw4 = (tid & 31) * 4;        // staging hw (0..124)
    const float* xb = x + (size_t)n * CC * HW + k0;

    float4 xr[2][4];
    f32x4 acc[8][2] = {};

    // prologue: load cs=0 tile
#pragma unroll
    for (int rr = 0; rr < 4; rr++)
        xr[0][rr] = *(const float4*)&xb[(size_t)(cst + 8 * rr) * HW + hw4];

#pragma unroll
    for (int cs = 0; cs < 8; cs++) {
        int cur = cs & 1, nxt = cur ^ 1;
        // stage current regs -> LDS (ds_write_b64 x2 per float4; 2-way conflicts max)
#pragma unroll
        for (int rr = 0; rr < 4; rr++) {
            int base = (cst + 8 * rr) * CPAD + hw4;
            *(float2*)&Xs[cur][base]     = make_float2(xr[cur][rr].x, xr[cur][rr].y);
            *(float2*)&Xs[cur][base + 2] = make_float2(xr[cur][rr].z, xr[cur][rr].w);
        }
        // issue next tile's global loads (in flight through barrier+compute)
        if (cs < 7) {
#pragma unroll
            for (int rr = 0; rr < 4; rr++)
                xr[nxt][rr] = *(const float4*)&xb[(size_t)((cs + 1) * 32 + cst + 8 * rr) * HW + hw4];
        }
        __syncthreads();
        // A-frags direct from L2-hot Wf
        short8 af[8];
#pragma unroll
        for (int m = 0; m < 8; m++) {
            uint4 t = *(const uint4*)&Wf[((cs * 4 + q) * 128 + m * 16 + li) * 8];
            af[m] = *(short8*)&t;
        }
        // B-frags: 8 stride-CPAD LDS reads each, fp32 -> bf16
        short8 bfr[2];
#pragma unroll
        for (int nt = 0; nt < 2; nt++) {
            int hw = w * 32 + nt * 16 + li;
            union { ushort u[8]; short8 s; } tmp;
#pragma unroll
            for (int p = 0; p < 4; p++) {
                int base = (q * 8 + 2 * p) * CPAD + hw;
                tmp.u[2 * p]     = f2bf(Xs[cur][base]);
                tmp.u[2 * p + 1] = f2bf(Xs[cur][base + CPAD]);
            }
            bfr[nt] = tmp.s;
        }
#pragma unroll
        for (int m = 0; m < 8; m++)
#pragma unroll
            for (int nt = 0; nt < 2; nt++)
                acc[m][nt] = __builtin_amdgcn_mfma_f32_16x16x32_bf16(af[m], bfr[nt], acc[m][nt], 0, 0, 0);
    }

    // epilogue: rows r = m*16 + q*4 + rr; cols = k0 + w*32 + nt*16 + li
    float ga[2];
#pragma unroll
    for (int nt = 0; nt < 2; nt++) {
        int col = k0 + w * 32 + nt * 16 + li;
        float e0 = edge[((size_t)n * 2 + 0) * HW + col];
        float e1 = edge[((size_t)n * 2 + 1) * HW + col];
        ga[nt] = 1.f + 1.f / (1.f + __expf(e0 - e1));
    }
    float rp[4][4];
#pragma unroll
    for (int m = 0; m < 8; m++) {
#pragma unroll
        for (int rr = 0; rr < 4; rr++) {
            int r = m * 16 + q * 4 + rr;
            if (m < 4) {               // xs rows
                float bv = bs[r];
#pragma unroll
                for (int nt = 0; nt < 2; nt++) {
                    int col = k0 + w * 32 + nt * 16 + li;
                    xsb[((size_t)n * SS + r) * HW + col] = f2bf(acc[m][nt][rr] + bv);
                }
            } else {                   // E rows
                int s = r - 64;
                float bv = bp[s];
                float sum = 0.f;
#pragma unroll
                for (int nt = 0; nt < 2; nt++) {
                    int col = k0 + w * 32 + nt * 16 + li;
                    float e = __expf((acc[m][nt][rr] + bv) * ga[nt]);
                    sum += e;
                    Eb[((size_t)n * SS + s) * HW + col] = f2bf(e);
                }
                rp[m - 4][rr] = sum;
            }
        }
    }
#pragma unroll
    for (int b = 1; b < 16; b <<= 1)
#pragma unroll
        for (int m = 0; m < 4; m++)
#pragma unroll
            for (int rr = 0; rr < 4; rr++)
                rp[m][rr] += __shfl_xor(rp[m][rr], b, 64);
    if (li == 0) {
#pragma unroll
        for (int m = 0; m < 4; m++)
#pragma unroll
            for (int rr = 0; rr < 4; rr++)
                atomicAdd(&rsum[n * SS + m * 16 + q * 4 + rr], rp[m][rr]);
    }
}

// ---------------- K2: MFMA graph: U = xs@E^T, P = E@E^T, split-K partials, pipelined ---------
// grid (NSPLIT, NB). Waves 0,1: U halves; waves 2,3: P halves. K/block = HW/NSPLIT = 288.
__global__ __launch_bounds__(256) void k_graph(const ushort* __restrict__ xsb,
                                               const ushort* __restrict__ Eb,
                                               float* __restrict__ Up,
                                               float* __restrict__ Pp) {
    int n = blockIdx.y, sp = blockIdx.x;
    int kbase = sp * (HW / NSPLIT);
    int tid = threadIdx.x, lane = tid & 63, w = tid >> 6;
    int q = lane >> 4, li = lane & 15;
    bool isP = w >= 2;
    int half = w & 1;
    const ushort* Arow = isP ? Eb : xsb;
    const int NITER = (HW / NSPLIT) / 32;   // 9
    f32x4 acc[2][4] = {};
    short8 af[2][2], bfr[2][4];
    {
        int kb = kbase + q * 8;
#pragma unroll
        for (int mt = 0; mt < 2; mt++) {
            int s = half * 32 + mt * 16 + li;
            uint4 t = *(const uint4*)&Arow[((size_t)n * SS + s) * HW + kb];
            af[0][mt] = *(short8*)&t;
        }
#pragma unroll
        for (int nt = 0; nt < 4; nt++) {
            int tt = nt * 16 + li;
            uint4 t = *(const uint4*)&Eb[((size_t)n * SS + tt) * HW + kb];
            bfr[0][nt] = *(short8*)&t;
        }
    }
#pragma unroll
    for (int ks = 0; ks < NITER; ks++) {
        int cur = ks & 1, nxt = cur ^ 1;
        if (ks < NITER - 1) {
            int kb = kbase + (ks + 1) * 32 + q * 8;
#pragma unroll
            for (int mt = 0; mt < 2; mt++) {
                int s = half * 32 + mt * 16 + li;
                uint4 t = *(const uint4*)&Arow[((size_t)n * SS + s) * HW + kb];
                af[nxt][mt] = *(short8*)&t;
            }
#pragma unroll
            for (int nt = 0; nt < 4; nt++) {
                int tt = nt * 16 + li;
                uint4 t = *(const uint4*)&Eb[((size_t)n * SS + tt) * HW + kb];
                bfr[nxt][nt] = *(short8*)&t;
            }
        }
#pragma unroll
        for (int mt = 0; mt < 2; mt++)
#pragma unroll
            for (int nt = 0; nt < 4; nt++)
                acc[mt][nt] = __builtin_amdgcn_mfma_f32_16x16x32_bf16(af[cur][mt], bfr[cur][nt], acc[mt][nt], 0, 0, 0);
    }
    float* dst = (isP ? Pp : Up) + ((size_t)sp * NB + n) * 4096;
#pragma unroll
    for (int mt = 0; mt < 2; mt++)
#pragma unroll
        for (int nt = 0; nt < 4; nt++)
#pragma unroll
            for (int rr = 0; rr < 4; rr++) {
                int row = half * 32 + mt * 16 + q * 4 + rr;
                int col = nt * 16 + li;
                dst[row * 64 + col] = acc[mt][nt][rr];
            }
}

// ---------------- K3: GCN + fold We (reduces U partials in-kernel) --------------
__global__ __launch_bounds__(256) void k_gcn(const float* __restrict__ Up,
                                             const float* __restrict__ rsum,
                                             const float* __restrict__ W1,
                                             const float* __restrict__ W2,
                                             const float* __restrict__ We,
                                             float* __restrict__ M,
                                             ushort* __restrict__ Mf) {
    __shared__ __align__(16) float A[64 * 68];
    __shared__ __align__(16) float B[64 * 68];
    __shared__ __align__(16) float Cb[64 * 68];
    __shared__ float rs[64];
    int n = blockIdx.x;
    int cc = blockIdx.y;
    int tid = threadIdx.x;
    int t0 = tid >> 4, t1 = tid & 15;
    if (tid < 64) rs[tid] = 1.0f / rsum[n * SS + tid];
    __syncthreads();
#pragma unroll
    for (int i = 0; i < 16; i++) {
        int idx = tid + i * 256;
        int r = idx >> 6, cth = idx & 63;
        float sum = 0.f;
#pragma unroll
        for (int sp = 0; sp < NSPLIT; sp++)
            sum += Up[((size_t)sp * NB + n) * 4096 + idx];
        A[cth * 68 + r] = sum * rs[cth];
        B[cth * 68 + r] = W1[idx];
    }
    __syncthreads();
    {
        float acc[4][4] = {};
        for (int j = 0; j < 64; j++) {
            float4 a4 = *(const float4*)&A[j * 68 + t0 * 4];
            float4 b4 = *(const float4*)&B[j * 68 + t1 * 4];
            float a[4] = {a4.x, a4.y, a4.z, a4.w};
            float b[4] = {b4.x, b4.y, b4.z, b4.w};
#pragma unroll
            for (int p = 0; p < 4; p++)
#pragma unroll
                for (int qq = 0; qq < 4; qq++) acc[p][qq] += a[p] * b[qq];
        }
#pragma unroll
        for (int p = 0; p < 4; p++)
#pragma unroll
            for (int qq = 0; qq < 4; qq++) {
                acc[p][qq] -= A[(t1 * 4 + qq) * 68 + (t0 * 4 + p)];
                Cb[(t0 * 4 + p) * 68 + t1 * 4 + qq] = acc[p][qq];
            }
    }
    __syncthreads();
#pragma unroll
    for (int i = 0; i < 16; i++) {
        int idx = tid + i * 256;
        int r = idx >> 6, cth = idx & 63;
        B[cth * 68 + r] = W2[idx];
    }
    __syncthreads();
    {
        float acc[4][4] = {};
        for (int j = 0; j < 64; j++) {
            float4 a4 = *(const float4*)&B[j * 68 + t0 * 4];
            float4 b4 = *(const float4*)&Cb[j * 68 + t1 * 4];
            float a[4] = {a4.x, a4.y, a4.z, a4.w};
            float b[4] = {b4.x, b4.y, b4.z, b4.w};
#pragma unroll
            for (int p = 0; p < 4; p++)
#pragma unroll
                for (int qq = 0; qq < 4; qq++) acc[p][qq] += a[p] * b[qq];
        }
        __syncthreads();
#pragma unroll
        for (int p = 0; p < 4; p++)
#pragma unroll
            for (int qq = 0; qq < 4; qq++)
                A[(t0 * 4 + p) * 68 + t1 * 4 + qq] = fmaxf(acc[p][qq], 0.f);
    }
    __syncthreads();
#pragma unroll
    for (int i = 0; i < 16; i++) {
        int idx = tid + i * 256;
        int c = idx >> 6, j = idx & 63;
        B[j * 68 + c] = We[(cc * 64 + c) * 64 + j];
    }
    __syncthreads();
    {
        float acc[4][4] = {};
        for (int j = 0; j < 64; j++) {
            float4 a4 = *(const float4*)&B[j * 68 + t0 * 4];
            float4 b4 = *(const float4*)&A[j * 68 + t1 * 4];
            float a[4] = {a4.x, a4.y, a4.z, a4.w};
            float b[4] = {b4.x, b4.y, b4.z, b4.w};
#pragma unroll
            for (int p = 0; p < 4; p++)
#pragma unroll
                for (int qq = 0; qq < 4; qq++) acc[p][qq] += a[p] * b[qq];
        }
#pragma unroll
        for (int p = 0; p < 4; p++) {
            int c = cc * 64 + t0 * 4 + p;
            float v[4];
#pragma unroll
            for (int qq = 0; qq < 4; qq++) v[qq] = acc[p][qq] * rs[t1 * 4 + qq];
            float4 st = {v[0], v[1], v[2], v[3]};
            *(float4*)&M[((size_t)n * CC + c) * 64 + t1 * 4] = st;
#pragma unroll
            for (int qq = 0; qq < 4; qq++) {
                int t = t1 * 4 + qq;
                Mf[(size_t)n * 16384 + ((t >> 3) * 256 + c) * 8 + (t & 7)] = f2bf(v[qq]);
            }
        }
    }
}

// ---------------- K4: BN stats partials: grid (NB, 8). Reduces Pp in-kernel. ----------------
// Qp[n][c] = m_c^T P m_c ; Sp[n][c] = sum_t M'[c][t]*rsum[t]
__global__ __launch_bounds__(256) void k_stats(const float* __restrict__ M,
                                               const float* __restrict__ Pp,
                                               const float* __restrict__ rsum,
                                               float* __restrict__ Qp,
                                               float* __restrict__ Sp) {
    __shared__ float Pl[4096];
    __shared__ float ms[32 * 64];
    __shared__ float rsl[64];
    int n = blockIdx.x, c0 = blockIdx.y * 32;
    int tid = threadIdx.x;
    for (int e = tid; e < 4096; e += 256) {
        float s = 0.f;
#pragma unroll
        for (int sp = 0; sp < NSPLIT; sp++)
            s += Pp[((size_t)sp * NB + n) * 4096 + e];
        Pl[e] = s;
    }
#pragma unroll
    for (int i = 0; i < 8; i++) {
        int idx = tid + i * 256;        // 0..2047
        ms[idx] = M[((size_t)n * CC + c0 + (idx >> 6)) * 64 + (idx & 63)];
    }
    if (tid < 64) rsl[tid] = rsum[n * SS + tid];
    __syncthreads();
    int cl = tid >> 3, sg = tid & 7;    // 32 channels x 8 threads
    const float* msr = &ms[cl * 64];
    float qa = 0.f;
#pragma unroll
    for (int s8 = 0; s8 < 8; s8++) {
        int s = sg * 8 + s8;
        float dot = 0.f;
#pragma unroll
        for (int t = 0; t < 64; t++) dot += Pl[s * 64 + t] * msr[t];
        qa += msr[s] * dot;
    }
    qa += __shfl_xor(qa, 1, 64);
    qa += __shfl_xor(qa, 2, 64);
    qa += __shfl_xor(qa, 4, 64);
    if (sg == 0) {
        float sa = 0.f;
#pragma unroll
        for (int t = 0; t < 64; t++) sa += msr[t] * rsl[t];
        Qp[n * CC + c0 + cl] = qa;
        Sp[n * CC + c0 + cl] = sa;
    }
}

// ---------------- K4b: finalize BN scale/bias (1 block) ----------------
__global__ __launch_bounds__(256) void k_bn(const float* __restrict__ Qp,
                                            const float* __restrict__ Sp,
                                            const float* __restrict__ gamma,
                                            const float* __restrict__ beta,
                                            float* __restrict__ sc,
                                            float* __restrict__ bi) {
    int c = threadIdx.x;
    float qtot = 0.f, stot = 0.f;
#pragma unroll
    for (int n = 0; n < NB; n++) {
        qtot += Qp[n * CC + c];
        stot += Sp[n * CC + c];
    }
    const float invM = 1.0f / ((float)NB * (float)HW);
    float mean = stot * invM;
    float var = qtot * invM - mean * mean;
    float s = gamma[c] * rsqrtf(var + EPS);
    sc[c] = s;
    bi[c] = beta[c] - s * mean;
}

// ---------------- K5: MFMA out: out = x + sc[c]*(M' @ E)[c,k] + bi[c] ----------------
// grid (72, NB): block 256c x 64hw, K=64 (2 MFMA steps). A direct from Mf; B via LDS.
__global__ __launch_bounds__(256) void k_out(const float* __restrict__ x,
                                             const ushort* __restrict__ Mf,
                                             const ushort* __restrict__ Eb,
                                             const float* __restrict__ sc,
                                             const float* __restrict__ bi,
                                             float* __restrict__ out) {
    __shared__ __align__(16) ushort Bl[8 * 64 * 8];    // [kq][n][8] = 8 KB
    int n = blockIdx.y, k0 = blockIdx.x * 64;
    int tid = threadIdx.x, lane = tid & 63, w = tid >> 6;
    int q = lane >> 4, li = lane & 15;
    {
        int nl = tid & 63, pr = tid >> 6;
#pragma unroll
        for (int kk = 0; kk < 2; kk++) {
            int kq = pr * 2 + kk;
            union { ushort u[8]; uint4 v; } tmp;
#pragma unroll
            for (int j = 0; j < 8; j++)
                tmp.u[j] = Eb[((size_t)n * SS + kq * 8 + j) * HW + k0 + nl];
            *(uint4*)&Bl[(kq * 64 + nl) * 8] = tmp.v;
        }
    }
    __syncthreads();
    f32x4 acc[4][4] = {};
#pragma unroll
    for (int ks = 0; ks < 2; ks++) {
        short8 af[4], bfr[4];
#pragma unroll
        for (int mt = 0; mt < 4; mt++) {
            int c = w * 64 + mt * 16 + li;
            uint4 t = *(const uint4*)&Mf[(size_t)n * 16384 + ((ks * 4 + q) * 256 + c) * 8];
            af[mt] = *(short8*)&t;
        }
#pragma unroll
        for (int nt = 0; nt < 4; nt++) {
            int nl = nt * 16 + li;
            uint4 t = *(const uint4*)&Bl[((ks * 4 + q) * 64 + nl) * 8];
            bfr[nt] = *(short8*)&t;
        }
#pragma unroll
        for (int mt = 0; mt < 4; mt++)
#pragma unroll
            for (int nt = 0; nt < 4; nt++)
                acc[mt][nt] = __builtin_amdgcn_mfma_f32_16x16x32_bf16(af[mt], bfr[nt], acc[mt][nt], 0, 0, 0);
    }
#pragma unroll
    for (int mt = 0; mt < 4; mt++) {
        float xv[4][4];
#pragma unroll
        for (int rr = 0; rr < 4; rr++) {
            int c = w * 64 + mt * 16 + q * 4 + rr;
            size_t base = ((size_t)n * CC + c) * HW + k0;
#pragma unroll
            for (int nt = 0; nt < 4; nt++)
                xv[rr][nt] = x[base + nt * 16 + li];
        }
#pragma unroll
        for (int rr = 0; rr < 4; rr++) {
            int c = w * 64 + mt * 16 + q * 4 + rr;
            float s_ = sc[c], bv = bi[c];
            size_t base = ((size_t)n * CC + c) * HW + k0;
#pragma unroll
            for (int nt = 0; nt < 4; nt++) {
                int col = nt * 16 + li;
                out[base + col] = xv[rr][nt] + s_ * acc[mt][nt][rr] + bv;
            }
        }
    }
}

extern "C" void kernel_launch(void* const* d_in, const int* in_sizes, int n_in,
                              void* d_out, int out_size, void* d_ws, size_t ws_size,
                              hipStream_t stream) {
    const float* x = (const float*)d_in[0];
    const float* edge = (const float*)d_in[1];
    const float* Ws = (const float*)d_in[2];
    const float* bs = (const float*)d_in[3];
    const float* Wp = (const float*)d_in[4];
    const float* bp = (const float*)d_in[5];
    const float* W1 = (const float*)d_in[6];
    const float* W2 = (const float*)d_in[7];
    const float* We = (const float*)d_in[8];
    const float* gamma = (const float*)d_in[9];
    const float* beta = (const float*)d_in[10];
    float* out = (float*)d_out;

    char* base = (char*)d_ws;
    ushort* Wf  = (ushort*)base;                    base += 65536;
    ushort* xsb = (ushort*)base;                    base += 9437184;
    ushort* Eb  = (ushort*)base;                    base += 9437184;
    float*  Up  = (float*)base;                     base += (size_t)NSPLIT * NB * 4096 * 4;
    float*  Pp  = (float*)base;                     base += (size_t)NSPLIT * NB * 4096 * 4;
    float*  rsum= (float*)base;                     base += 4096;
    float*  M   = (float*)base;                     base += 1048576;
    ushort* Mf  = (ushort*)base;                    base += 524288;
    float*  Qp  = (float*)base;                     base += 16384;
    float*  Sp  = (float*)base;                     base += 16384;
    float*  sc  = (float*)base;                     base += 1024;
    float*  bi  = (float*)base;                     base += 1024;

    hipMemsetAsync(rsum, 0, 1024 * sizeof(float), stream);
    k_wf<<<128, 256, 0, stream>>>(Ws, Wp, Wf);
    k_proj<<<dim3(36, NB), 256, 0, stream>>>(x, Wf, bs, bp, edge, xsb, Eb, rsum);
    k_graph<<<dim3(NSPLIT, NB), 256, 0, stream>>>(xsb, Eb, Up, Pp);
    k_gcn<<<dim3(NB, 4), 256, 0, stream>>>(Up, rsum, W1, W2, We, M, Mf);
    k_stats<<<dim3(NB, 8), 256, 0, stream>>>(M, Pp, rsum, Qp, Sp);
    k_bn<<<1, 256, 0, stream>>>(Qp, Sp, gamma, beta, sc, bi);
    k_out<<<dim3(72, NB), 256, 0, stream>>>(x, Mf, Eb, sc, bi, out);
}